// Round 4
// baseline (362.355 us; speedup 1.0000x reference)
//
#include <hip/hip_runtime.h>

// TMoE layer: y = SCALING * (softmax(x@route_w^T) gated low-rank mixture)
// R7: FULL FUSION. One kernel, 256 blocks (1/CU), 128 tokens/block:
//   phase1: c[128][64]+logits via LDS-staged x chunks (32KB in flight/CU,
//           fixes the latency-bound reg-prefetch k1: 80us -> ~25us BW-bound)
//   transition: softmax -> snapshot c/route to regs -> build gated A-tile
//           [128][512] bf16 in LDS (stride 520, conflict-free). g and c
//           never touch HBM.
//   phase2: y = A @ Bflat^T; B reg-prefetched from L2-resident bc into a
//           single 18KB LDS buffer (R6-k2's proven stride-72 + MFMA loop).
// LDS 151,552 B: A-region 133,120 (aliases: x-chunk 32K | cAll 43K |
// route 4K during phase1) + B-region 18,432. The ~160us of harness
// fillBuffer poison (2x80us, 536MB each) is fixed overhead we can't touch.

#define NTOK    32768
#define DIM     1024
#define NW1     80          // 64 c-rows + 8 router rows + 8 zero pad
#define GDIM    512         // E*R
#define OUTD    1024
#define SCALING 0.25f

#define A_STRIDE 520        // halfwords per gated-A row (16B aligned, pad 8)
#define B_OFF    133120     // byte offset of B staging region
#define CALL_OFF 32768      // byte offset of cAll scratch (f32 [128][84])
#define CALL_STR 84
#define ROUTE_OFF 75776     // byte offset of route scratch (f32 [128][8])
#define LDS_U4   (151552/16)

typedef __bf16 bf16x8 __attribute__((ext_vector_type(8)));
typedef float  f32x4  __attribute__((ext_vector_type(4)));

static __device__ __forceinline__ unsigned short f2bf(float f) {
    union { float f; unsigned u; } v; v.f = f;
    unsigned r = v.u + 0x7FFFu + ((v.u >> 16) & 1u);   // RNE
    return (unsigned short)(r >> 16);
}

// ---------------- weight conversion (R0-proven, unchanged) ----------------
__global__ __launch_bounds__(256) void conv_w1(const float* __restrict__ A,
                                               const float* __restrict__ Rw,
                                               unsigned short* __restrict__ w1) {
    int i = blockIdx.x * 256 + threadIdx.x;
    if (i >= NW1 * DIM) return;
    int row = i >> 10, col = i & (DIM - 1);
    float v = 0.0f;
    if (row < 64)      v = A[(row << 10) + col];
    else if (row < 72) v = Rw[((row - 64) << 10) + col];
    w1[i] = f2bf(v);
}

__global__ __launch_bounds__(256) void conv_b(const float* __restrict__ B,
                                              unsigned short* __restrict__ bc) {
    int i = blockIdx.x * 256 + threadIdx.x;     // i = o*512 + e*64 + r
    if (i >= OUTD * GDIM) return;
    int o = i >> 9, er = i & 511;
    int e = er >> 6, r = er & 63;
    bc[i] = f2bf(B[(e << 16) + (o << 6) + r]);  // B[e][o][r], strides 65536/64/1
}

// ---------------- fused kernel ----------------
__global__ __launch_bounds__(256) void fused(
        const float* __restrict__ x,
        const unsigned short* __restrict__ w1,
        const unsigned short* __restrict__ bc,
        float* __restrict__ y) {
    __shared__ uint4 smu[LDS_U4];
    unsigned char* sm = (unsigned char*)smu;
    unsigned short* Ab = (unsigned short*)sm;            // gated A [128][520]
    unsigned short* Bb = (unsigned short*)(sm + B_OFF);  // B tile [128][72]
    float* xs   = (float*)sm;                            // x chunk [128][64] (aliased)
    float* cAll = (float*)(sm + CALL_OFF);               // c+logits [128][84] (aliased)
    float* rL   = (float*)(sm + ROUTE_OFF);              // route [128][8] (aliased)

    const int tid  = threadIdx.x;
    const int wv   = tid >> 6;
    const int lane = tid & 63;
    const int quad = lane >> 4;
    const int l16  = lane & 15;
    const int t0   = blockIdx.x << 7;      // 128 tokens/block

    // ================= phase 1: c + router logits =================
    f32x4 acc1[2][5];
#pragma unroll
    for (int tg = 0; tg < 2; ++tg)
#pragma unroll
        for (int n = 0; n < 5; ++n) acc1[tg][n] = (f32x4){0.f, 0.f, 0.f, 0.f};

    // staging map: thread covers rows srow+16i (i=0..7), 16B chunk sq of
    // each 64-f32 chunk row. XOR swizzle key = row&15 = srow (16i keeps low
    // bits) -> read side key = l16 = row&15: same involution both sides.
    const int srow = tid >> 4;             // 0..15
    const int sq   = tid & 15;
    const int xq   = (sq ^ srow) << 2;     // swizzled dword offset in row
    const float* xsrc = x + (size_t)(t0 + srow) * DIM + (sq << 2);
    const unsigned short* wp = w1 + (l16 << 10) + (quad << 3);

    f32x4 xr[8];
#pragma unroll
    for (int i = 0; i < 8; ++i)
        xr[i] = *(const f32x4*)(xsrc + (size_t)(i << 4) * DIM);

    for (int c = 0; c < 16; ++c) {
        __syncthreads();                   // previous chunk's readers done
#pragma unroll
        for (int i = 0; i < 8; ++i)
            *(f32x4*)(xs + ((srow + (i << 4)) << 6) + xq) = xr[i];
        __syncthreads();                   // chunk visible
        if (c < 15) {
            const float* nx = xsrc + ((c + 1) << 6);
#pragma unroll
            for (int i = 0; i < 8; ++i)
                xr[i] = *(const f32x4*)(nx + (size_t)(i << 4) * DIM);
        }
        const int kc0 = c << 6;
#pragma unroll
        for (int kk = 0; kk < 2; ++kk) {
            bf16x8 wfr[5];
#pragma unroll
            for (int n = 0; n < 5; ++n)
                wfr[n] = *(const bf16x8*)(wp + (n << 14) + kc0 + (kk << 5));
            bf16x8 af[2];
#pragma unroll
            for (int tg = 0; tg < 2; ++tg) {
                const int row = (wv << 5) + (tg << 4) + l16;
                const int cb  = (kk << 3) + (quad << 1);
                const int ch0 = cb ^ (row & 15);
                const int ch1 = (cb + 1) ^ (row & 15);
                f32x4 a0 = *(const f32x4*)(xs + (row << 6) + (ch0 << 2));
                f32x4 a1 = *(const f32x4*)(xs + (row << 6) + (ch1 << 2));
#pragma unroll
                for (int m2 = 0; m2 < 4; ++m2) {
                    af[tg][m2]     = (__bf16)a0[m2];
                    af[tg][4 + m2] = (__bf16)a1[m2];
                }
            }
#pragma unroll
            for (int tg = 0; tg < 2; ++tg)
#pragma unroll
                for (int n = 0; n < 5; ++n)
                    acc1[tg][n] = __builtin_amdgcn_mfma_f32_16x16x32_bf16(af[tg], wfr[n], acc1[tg][n], 0, 0, 0);
        }
    }

    // D layout: row = quad*4+reg (token), col = l16 (feature)
#pragma unroll
    for (int tg = 0; tg < 2; ++tg)
#pragma unroll
        for (int n = 0; n < 5; ++n)
#pragma unroll
            for (int r = 0; r < 4; ++r)
                cAll[((wv << 5) + (tg << 4) + (quad << 2) + r) * CALL_STR + (n << 4) + l16] = acc1[tg][n][r];
    __syncthreads();

    // softmax * SCALING
    if (tid < 128) {
        float lg[8]; float m = -1e30f;
#pragma unroll
        for (int e = 0; e < 8; ++e) { lg[e] = cAll[tid * CALL_STR + 64 + e]; m = fmaxf(m, lg[e]); }
        float s = 0.f;
#pragma unroll
        for (int e = 0; e < 8; ++e) { lg[e] = expf(lg[e] - m); s += lg[e]; }
        float inv = SCALING / s;
#pragma unroll
        for (int e = 0; e < 8; ++e) rL[tid * 8 + e] = lg[e] * inv;
    }
    __syncthreads();

    // snapshot my c-slice + route to regs (A-build below overwrites scratch)
    const int stok = tid >> 1;
    const int sf0  = (tid & 1) << 5;       // 0 or 32 (feature half)
    f32x4 cs[8];
#pragma unroll
    for (int j = 0; j < 8; ++j)
        cs[j] = *(const f32x4*)(cAll + stok * CALL_STR + sf0 + (j << 2));
    float rr[8];
#pragma unroll
    for (int e = 0; e < 8; ++e) rr[e] = rL[stok * 8 + e];
    __syncthreads();                       // all snapshots done

    // build gated A tile: A[tok][e*64 + r] = route[tok][e] * c[tok][r]
#pragma unroll
    for (int e = 0; e < 8; ++e) {
        const float rv = rr[e];
#pragma unroll
        for (int j = 0; j < 4; ++j) {
            bf16x8 pk;
#pragma unroll
            for (int m2 = 0; m2 < 4; ++m2) {
                pk[m2]     = (__bf16)(rv * cs[(j << 1)][m2]);
                pk[4 + m2] = (__bf16)(rv * cs[(j << 1) + 1][m2]);
            }
            *(bf16x8*)(Ab + stok * A_STRIDE + (e << 6) + sf0 + (j << 3)) = pk;
        }
    }

    // ================= phase 2: y = A @ Bflat^T =================
    const int brow = tid >> 3;             // +32 per i
    const int bkq  = tid & 7;
    uint4 bq[4];
#pragma unroll
    for (int i = 0; i < 4; ++i)            // prologue: (n0=0, kc=0)
        bq[i] = *(const uint4*)(bc + (size_t)(brow + (i << 5)) * GDIM + (bkq << 3));
    __syncthreads();                       // A-tile ready

    const int mo = (wv & 1) << 6;
    const int no = (wv >> 1) << 6;

    for (int n0 = 0; n0 < 8; ++n0) {
        f32x4 acc[4][4];
#pragma unroll
        for (int i = 0; i < 4; ++i)
#pragma unroll
            for (int j = 0; j < 4; ++j) acc[i][j] = (f32x4){0.f, 0.f, 0.f, 0.f};

        for (int kc = 0; kc < 8; ++kc) {
            __syncthreads();               // previous B readers done
#pragma unroll
            for (int i = 0; i < 4; ++i)
                *(uint4*)(Bb + (brow + (i << 5)) * 72 + (bkq << 3)) = bq[i];
            __syncthreads();               // B tile visible
            // issue next B-tile loads (L2-resident bc)
            const int last = (n0 == 7) & (kc == 7);
            const int n0n = (kc == 7) ? n0 + 1 : n0;
            const int kcn = (kc == 7) ? 0 : kc + 1;
            if (!last) {
#pragma unroll
                for (int i = 0; i < 4; ++i)
                    bq[i] = *(const uint4*)(bc + (size_t)((n0n << 7) + brow + (i << 5)) * GDIM + (kcn << 6) + (bkq << 3));
            }
#pragma unroll
            for (int kk = 0; kk < 2; ++kk) {
                bf16x8 af[4], bfr[4];
#pragma unroll
                for (int i = 0; i < 4; ++i)
                    af[i] = *(const bf16x8*)(Ab + (mo + (i << 4) + l16) * A_STRIDE + (kc << 6) + (kk << 5) + (quad << 3));
#pragma unroll
                for (int j = 0; j < 4; ++j)
                    bfr[j] = *(const bf16x8*)(Bb + (no + (j << 4) + l16) * 72 + (kk << 5) + (quad << 3));
#pragma unroll
                for (int i = 0; i < 4; ++i)
#pragma unroll
                    for (int j = 0; j < 4; ++j)
                        acc[i][j] = __builtin_amdgcn_mfma_f32_16x16x32_bf16(af[i], bfr[j], acc[i][j], 0, 0, 0);
            }
        }
        // store this n-chunk of y
#pragma unroll
        for (int i = 0; i < 4; ++i)
#pragma unroll
            for (int j = 0; j < 4; ++j)
#pragma unroll
                for (int r = 0; r < 4; ++r) {
                    int row = t0 + mo + (i << 4) + (quad << 2) + r;
                    int col = (n0 << 7) + no + (j << 4) + l16;
                    y[(size_t)row * OUTD + col] = acc[i][j][r];
                }
    }
}

extern "C" void kernel_launch(void* const* d_in, const int* in_sizes, int n_in,
                              void* d_out, int out_size, void* d_ws, size_t ws_size,
                              hipStream_t stream) {
    const float* x  = (const float*)d_in[0];   // [8,4096,1024]
    const float* rw = (const float*)d_in[1];   // [8,1024]
    const float* A  = (const float*)d_in[2];   // [64,1024]
    const float* B  = (const float*)d_in[3];   // [8,1024,64]
    float* y = (float*)d_out;                  // [8,4096,1024] fp32

    unsigned short* w1 = (unsigned short*)d_ws;   // [80][1024] bf16
    unsigned short* bc = w1 + NW1 * DIM;          // [1024][512] bf16

    conv_w1<<<(NW1 * DIM + 255) / 256, 256, 0, stream>>>(A, rw, w1);
    conv_b<<<(OUTD * GDIM + 255) / 256, 256, 0, stream>>>(B, bc);
    fused<<<NTOK / 128, 256, 0, stream>>>(x, w1, bc, y);
}

// Round 5
// 296.923 us; speedup vs baseline: 1.2204x; 1.2204x over previous
//
#include <hip/hip_runtime.h>

// TMoE layer: y = SCALING * (softmax(x@route_w^T) gated low-rank mixture)
// R8: revert to R6 two-kernel base (fused R7 was 1 block/CU -> no TLP).
//  k1 change: w1 pre-swizzled into FRAGMENT-CONTIGUOUS layout w1t
//    (each (k-chunk,n-group) frag = contiguous 1KB wave-load, L1-broadcast
//    across waves). Theory: k1 is VMEM-transaction-bound -- every w-frag
//    load was a 16-row scatter (16 cache lines/instr), 5 of 7 loads/iter.
//  k2 rewrite: A-side entirely in REGISTERS (c 16 f32 + route 8 f32 per
//    m-frag per lane = 96 VGPR, k-loop builds af = bf16(route*c) in-reg,
//    R5-proven math). B double-buffered in LDS (2x16KB) from pre-XOR-
//    swizzled bcs (conv_b bakes swizzle; ds_read XORs with (row&7)<<3 ->
//    bank-balanced). ONE barrier per kc. launch_bounds(256,2), ~230 VGPR.

#define NTOK    32768
#define DIM     1024
#define GDIM    512         // E*R
#define OUTD    1024
#define SCALING 0.25f

typedef __bf16 bf16x8 __attribute__((ext_vector_type(8)));
typedef float  f32x4  __attribute__((ext_vector_type(4)));

static __device__ __forceinline__ unsigned short f2bf(float f) {
    union { float f; unsigned u; } v; v.f = f;
    unsigned r = v.u + 0x7FFFu + ((v.u >> 16) & 1u);   // RNE
    return (unsigned short)(r >> 16);
}

// ---------------- conv_w1: fragment-contiguous w1t ----------------
// w1t[((kc2*5 + n)*64 + lane)*8 + j] = w1[n*16 + (lane&15)]
//                                        [kc2*32 + (lane>>4)*8 + j]
// rows 0..63 = A, 64..71 = Rw, 72..79 = zero pad. 32 kc2 x 5 n x 512 hw.
__global__ __launch_bounds__(256) void conv_w1(const float* __restrict__ A,
                                               const float* __restrict__ Rw,
                                               unsigned short* __restrict__ w1t) {
    int i = blockIdx.x * 256 + threadIdx.x;
    if (i >= 160 * 512) return;                 // 81920
    int j    = i & 7;
    int lane = (i >> 3) & 63;
    int g    = i >> 9;                          // kc2*5 + n
    int n    = g % 5;
    int kc2  = g / 5;
    int row  = (n << 4) + (lane & 15);
    int k    = (kc2 << 5) + ((lane >> 4) << 3) + j;
    float v = 0.0f;
    if (row < 64)      v = A[(row << 10) + k];
    else if (row < 72) v = Rw[((row - 64) << 10) + k];
    w1t[i] = f2bf(v);
}

// ---------------- conv_b: XOR-swizzled bcs ----------------
// logical bc[o][e*64+r] = B[e][o][r]; stored at r' = r ^ ((o&7)<<3) so the
// k2 ds_read (same XOR) is bank-balanced while staging stays linear.
__global__ __launch_bounds__(256) void conv_b(const float* __restrict__ B,
                                              unsigned short* __restrict__ bcs) {
    int i = blockIdx.x * 256 + threadIdx.x;     // i = o*512 + e*64 + r
    if (i >= OUTD * GDIM) return;
    int o = i >> 9, er = i & 511;
    int e = er >> 6, r = er & 63;
    int w = (i - r) + (r ^ ((o & 7) << 3));     // swizzled position
    bcs[w] = f2bf(B[(e << 16) + (o << 6) + r]); // B[e][o][r]
}

// ---------------- k1: routing + compress (R8: contiguous w-frags) -------
// 32 tok/block, 4 waves = (2 token groups) x (2 K-halves). Barrier-free
// K-loop, register prefetch: x depth-4, w1t depth-2 (now 1KB contiguous
// wave-loads, L1-broadcast). Outputs cout f32 [NTOK][64], rout f32
// [NTOK][8] (softmax*SCALING). One barrier total.
__global__ __launch_bounds__(256, 4) void k1_route_compress(
        const float* __restrict__ x,
        const unsigned short* __restrict__ w1t,
        float* __restrict__ cout,
        float* __restrict__ rout) {
    __shared__ float cAll[2][32][84];

    const int tid  = threadIdx.x;
    const int wave = tid >> 6;
    const int lane = tid & 63;
    const int quad = lane >> 4;
    const int l16  = lane & 15;
    const int t0   = blockIdx.x << 5;          // 32 tokens/block

    const int tokw  = (wave >> 1) << 4;        // 0 or 16
    const int khalf = wave & 1;                // K-half this wave owns
    const int kb0   = khalf << 9;              // 0 or 512

    f32x4 acc[5];
#pragma unroll
    for (int n = 0; n < 5; ++n) acc[n] = (f32x4){0.f, 0.f, 0.f, 0.f};

    const float* xp = x + (size_t)(t0 + tokw + l16) * DIM + kb0 + (quad << 3);
    // fragment-contiguous w base: khalf*16 chunks * 5 groups * 512 hw
    const unsigned short* wp = w1t + ((size_t)(khalf * 80) << 9) + (lane << 3);

    // rotating prefetch slots (statically indexed after full unroll)
    float4 xa[4], xb[4];
    bf16x8 wv[2][5];
#pragma unroll
    for (int s = 0; s < 4; ++s) {
        xa[s] = *(const float4*)(xp + (s << 5));
        xb[s] = *(const float4*)(xp + (s << 5) + 4);
    }
#pragma unroll
    for (int s = 0; s < 2; ++s)
#pragma unroll
        for (int n = 0; n < 5; ++n)
            wv[s][n] = *(const bf16x8*)(wp + ((s * 5 + n) << 9));

#pragma unroll
    for (int kk = 0; kk < 16; ++kk) {
        const int sx = kk & 3;
        const int sw = kk & 1;
        const float4 ca = xa[sx];
        const float4 cb = xb[sx];
        bf16x8 bfr[5];
#pragma unroll
        for (int n = 0; n < 5; ++n) bfr[n] = wv[sw][n];

        if (kk + 4 < 16) {
            xa[sx] = *(const float4*)(xp + ((kk + 4) << 5));
            xb[sx] = *(const float4*)(xp + ((kk + 4) << 5) + 4);
        }
        if (kk + 2 < 16) {
#pragma unroll
            for (int n = 0; n < 5; ++n)
                wv[sw][n] = *(const bf16x8*)(wp + (((kk + 2) * 5 + n) << 9));
        }

        bf16x8 af;
        af[0] = (__bf16)ca.x; af[1] = (__bf16)ca.y;
        af[2] = (__bf16)ca.z; af[3] = (__bf16)ca.w;
        af[4] = (__bf16)cb.x; af[5] = (__bf16)cb.y;
        af[6] = (__bf16)cb.z; af[7] = (__bf16)cb.w;
#pragma unroll
        for (int n = 0; n < 5; ++n)
            acc[n] = __builtin_amdgcn_mfma_f32_16x16x32_bf16(af, bfr[n], acc[n], 0, 0, 0);
    }

    // D layout: row = quad*4+reg (token), col = l16 (feature)
#pragma unroll
    for (int n = 0; n < 5; ++n)
#pragma unroll
        for (int r = 0; r < 4; ++r)
            cAll[khalf][tokw + (quad << 2) + r][(n << 4) + l16] = acc[n][r];
    __syncthreads();

    if (tid < 32) {
        float lg[8]; float m = -1e30f;
#pragma unroll
        for (int e = 0; e < 8; ++e) {
            lg[e] = cAll[0][tid][64 + e] + cAll[1][tid][64 + e];
            m = fmaxf(m, lg[e]);
        }
        float s = 0.f;
#pragma unroll
        for (int e = 0; e < 8; ++e) { lg[e] = expf(lg[e] - m); s += lg[e]; }
        float inv = SCALING / s;
        float4 r0v = (float4){lg[0] * inv, lg[1] * inv, lg[2] * inv, lg[3] * inv};
        float4 r1v = (float4){lg[4] * inv, lg[5] * inv, lg[6] * inv, lg[7] * inv};
        float* rp = rout + (size_t)(t0 + tid) * 8;
        *(float4*)(rp)     = r0v;
        *(float4*)(rp + 4) = r1v;
    }

    // c write: 32 tok x 64 f32 = 256 threads x 8 f32
    {
        int t  = tid >> 3;
        int c0 = (tid & 7) << 3;
        f32x4 a0 = *(const f32x4*)&cAll[0][t][c0];
        f32x4 a1 = *(const f32x4*)&cAll[0][t][c0 + 4];
        f32x4 b0 = *(const f32x4*)&cAll[1][t][c0];
        f32x4 b1 = *(const f32x4*)&cAll[1][t][c0 + 4];
        f32x4 s0 = a0 + b0, s1 = a1 + b1;
        float* cp = cout + (size_t)(t0 + t) * 64 + c0;
        *(f32x4*)(cp)     = s0;
        *(f32x4*)(cp + 4) = s1;
    }
}

// ---------------- k2: y = gated(c,route) @ Bflat^T (R8) ----------------
// 128x128 tile, 4 waves x (64x64 = 4x4 frags). A-side fully in registers:
// per lane, per m-frag i (row = m0+mo+i*16+l16): c[row][quad*8..+8] and
// c[row][32+quad*8..+8] (cr) + route[row][0..8] (rr). af rebuilt per kc as
// bf16(route[kc]*c) -- identical rounding to R6. B: double-buffered LDS
// [2][128][64] from swizzled bcs, linear stage, XOR ds_read, ONE barrier
// per kc (write other buffer while current is read).
__global__ __launch_bounds__(256, 2) void k2_up(
        const float* __restrict__ cw,
        const float* __restrict__ rt,
        const unsigned short* __restrict__ bcs,
        float* __restrict__ y) {
    __shared__ unsigned short Bb[2][128 * 64];

    const int tid  = threadIdx.x;
    const int wave = tid >> 6;
    const int lane = tid & 63;
    const int quad = lane >> 4;
    const int l16  = lane & 15;

    const int m0 = (blockIdx.x & 255) << 7;
    const int n0 = (blockIdx.x >> 8) << 7;
    const int mo = (wave & 1) << 6;
    const int no = (wave >> 1) << 6;

    // ---- one-time: c/route slices to registers ----
    f32x4 cr[4][4];      // [i][kk*2+half]
    f32x4 rr[4][2];      // [i][e-quad]
#pragma unroll
    for (int i = 0; i < 4; ++i) {
        const float* cp = cw + (size_t)(m0 + mo + (i << 4) + l16) * 64 + (quad << 3);
        cr[i][0] = *(const f32x4*)(cp);
        cr[i][1] = *(const f32x4*)(cp + 4);
        cr[i][2] = *(const f32x4*)(cp + 32);
        cr[i][3] = *(const f32x4*)(cp + 36);
        const float* rp = rt + (size_t)(m0 + mo + (i << 4) + l16) * 8;
        rr[i][0] = *(const f32x4*)(rp);
        rr[i][1] = *(const f32x4*)(rp + 4);
    }

    f32x4 acc[4][4];
#pragma unroll
    for (int i = 0; i < 4; ++i)
#pragma unroll
        for (int j = 0; j < 4; ++j) acc[i][j] = (f32x4){0.f, 0.f, 0.f, 0.f};

    const unsigned short* bsrc = bcs + (size_t)n0 * GDIM;

    // prologue: stage kc=0 into buffer 0 (linear copy; data pre-swizzled)
    {
        uint4 bq[4];
#pragma unroll
        for (int i = 0; i < 4; ++i) {
            int idx = tid + (i << 8);            // 0..1023
            int row = idx >> 3, c8 = idx & 7;
            bq[i] = *(const uint4*)(bsrc + (size_t)row * GDIM + (c8 << 3));
        }
#pragma unroll
        for (int i = 0; i < 4; ++i) {
            int idx = tid + (i << 8);
            int row = idx >> 3, c8 = idx & 7;
            *(uint4*)(&Bb[0][(row << 6) + (c8 << 3)]) = bq[i];
        }
    }
    __syncthreads();

    const int key = (l16 & 7) << 3;              // ds_read swizzle key (hw)

    for (int kc = 0; kc < 8; ++kc) {
        uint4 bq[4];
        if (kc < 7) {                            // issue next-tile loads early
#pragma unroll
            for (int i = 0; i < 4; ++i) {
                int idx = tid + (i << 8);
                int row = idx >> 3, c8 = idx & 7;
                bq[i] = *(const uint4*)(bsrc + (size_t)row * GDIM + ((kc + 1) << 6) + (c8 << 3));
            }
        }
        const unsigned short* bb = &Bb[kc & 1][0];
#pragma unroll
        for (int kk = 0; kk < 2; ++kk) {
            bf16x8 af[4];
#pragma unroll
            for (int i = 0; i < 4; ++i) {
                const float rv = rr[i][kc >> 2][kc & 3];
                const f32x4 c0 = cr[i][(kk << 1)];
                const f32x4 c1 = cr[i][(kk << 1) + 1];
#pragma unroll
                for (int m2 = 0; m2 < 4; ++m2) {
                    af[i][m2]     = (__bf16)(rv * c0[m2]);
                    af[i][4 + m2] = (__bf16)(rv * c1[m2]);
                }
            }
            bf16x8 bfr[4];
#pragma unroll
            for (int j = 0; j < 4; ++j) {
                const int row = no + (j << 4) + l16;
                const int c6  = ((kk << 5) + (quad << 3)) ^ key;
                bfr[j] = *(const bf16x8*)(bb + (row << 6) + c6);
            }
#pragma unroll
            for (int i = 0; i < 4; ++i)
#pragma unroll
                for (int j = 0; j < 4; ++j)
                    acc[i][j] = __builtin_amdgcn_mfma_f32_16x16x32_bf16(af[i], bfr[j], acc[i][j], 0, 0, 0);
        }
        if (kc < 7) {
#pragma unroll
            for (int i = 0; i < 4; ++i) {
                int idx = tid + (i << 8);
                int row = idx >> 3, c8 = idx & 7;
                *(uint4*)(&Bb[(kc + 1) & 1][(row << 6) + (c8 << 3)]) = bq[i];
            }
            __syncthreads();                     // one barrier per kc
        }
    }

#pragma unroll
    for (int i = 0; i < 4; ++i)
#pragma unroll
        for (int j = 0; j < 4; ++j)
#pragma unroll
            for (int r = 0; r < 4; ++r) {
                int row = m0 + mo + (i << 4) + (quad << 2) + r;
                int col = n0 + no + (j << 4) + l16;
                y[(size_t)row * OUTD + col] = acc[i][j][r];
            }
}

extern "C" void kernel_launch(void* const* d_in, const int* in_sizes, int n_in,
                              void* d_out, int out_size, void* d_ws, size_t ws_size,
                              hipStream_t stream) {
    const float* x  = (const float*)d_in[0];   // [8,4096,1024]
    const float* rw = (const float*)d_in[1];   // [8,1024]
    const float* A  = (const float*)d_in[2];   // [64,1024]
    const float* B  = (const float*)d_in[3];   // [8,1024,64]
    float* y = (float*)d_out;                  // [8,4096,1024] fp32

    float* cw = (float*)d_ws;                          // [32768][64] f32
    float* rt = cw + (size_t)NTOK * 64;                // [32768][8] f32
    unsigned short* w1t = (unsigned short*)(rt + (size_t)NTOK * 8);  // 160KB
    unsigned short* bcs = w1t + 160 * 512;             // [1024][512] bf16 swz

    conv_w1<<<(160 * 512 + 255) / 256, 256, 0, stream>>>(A, rw, w1t);
    conv_b<<<(OUTD * GDIM + 255) / 256, 256, 0, stream>>>(B, bcs);
    k1_route_compress<<<NTOK / 32, 256, 0, stream>>>(x, w1t, cw, rt);
    k2_up<<<(NTOK / 128) * (OUTD / 128), 256, 0, stream>>>(cw, rt, bcs, y);
}